// Round 1
// 147.917 us; speedup vs baseline: 1.0890x; 1.0890x over previous
//
#include <hip/hip_runtime.h>
#include <hip/hip_bf16.h>

typedef __bf16 bf16x8 __attribute__((ext_vector_type(8)));
typedef __bf16 bf16x4 __attribute__((ext_vector_type(4)));
typedef _Float16 half8 __attribute__((ext_vector_type(8)));
typedef _Float16 half4 __attribute__((ext_vector_type(4)));
typedef _Float16 half2v __attribute__((ext_vector_type(2)));
typedef float f32x4 __attribute__((ext_vector_type(4)));
typedef float f32x16 __attribute__((ext_vector_type(16)));

#define NROW 3072
#define NF 512            // IN_F == H*D == 512
#define NH 8
#define ND 64

// Order-preserving float<->uint key for atomicMax over signed floats.
__device__ __forceinline__ unsigned gat_enc_key(float f) {
    unsigned u = __float_as_uint(f);
    return (f < 0.f) ? ~u : (u | 0x80000000u);
}
__device__ __forceinline__ float gat_dec_key(unsigned k) {
    unsigned u = (k & 0x80000000u) ? (k ^ 0x80000000u) : ~k;
    return __uint_as_float(u);
}

// ---------------------------------------------------------------------------
// Stage 0 (merged prep): blocks 0..1791 convert x,W fp32->bf16 (float4);
// blocks 1792..4863 bitpack (adj>0 || j==i) into bits[3072][96] (1.18 MB).
// ---------------------------------------------------------------------------
__global__ __launch_bounds__(256) void gat_prep(const float* __restrict__ x,
                                                const float* __restrict__ W,
                                                const int* __restrict__ adj,
                                                __bf16* __restrict__ xb,
                                                __bf16* __restrict__ Wb,
                                                unsigned long long* __restrict__ bits64,
                                                unsigned* __restrict__ maxkey) {
    if (blockIdx.x == 0 && threadIdx.x < NH) maxkey[threadIdx.x] = 0u;
    if (blockIdx.x < 1792) {
        int k = blockIdx.x * 256 + threadIdx.x;
        const float4* s; __bf16* d;
        if (k < 393216) { s = (const float4*)x; d = xb; }
        else { k -= 393216;  s = (const float4*)W; d = Wb; }
        float4 v = s[k];
        bf16x4 o = { (__bf16)v.x, (__bf16)v.y, (__bf16)v.z, (__bf16)v.w };
        *reinterpret_cast<bf16x4*>(d + k * 4) = o;
    } else {
        int i = blockIdx.x - 1792;
        int wave = threadIdx.x >> 6;
        int lane = threadIdx.x & 63;
        const int* row = adj + i * NROW;
#pragma unroll
        for (int it = 0; it < 12; ++it) {
            int base = wave * 768 + it * 64;
            int j = base + lane;
            bool pred = (row[j] > 0) || (j == i);
            unsigned long long bal = __ballot(pred);
            if (lane == 0) bits64[i * 48 + (base >> 6)] = bal;
        }
    }
}

// ---------------------------------------------------------------------------
// Stage 1: h = x @ W^T (bf16 MFMA); write hT (per-head d-major) as FP16 via
// LDS transpose. 1536 blocks x 4 wave-tiles (16x16).
// ---------------------------------------------------------------------------
__global__ __launch_bounds__(256) void gat_gemm(const __bf16* __restrict__ xb,
                                                const __bf16* __restrict__ Wb,
                                                _Float16* __restrict__ hT) {
    __shared__ _Float16 tile[4][16][17];
    int wave = threadIdx.x >> 6;
    int lane = threadIdx.x & 63;
    int t = blockIdx.x * 4 + wave;          // 6144 tiles: 192 i-tiles x 32 o-tiles
    int i0 = (t >> 5) << 4;
    int o0 = (t & 31) << 4;
    int fr = lane & 15;
    int quad = lane >> 4;

    const bf16x8* xa = reinterpret_cast<const bf16x8*>(xb + (i0 + fr) * NF + quad * 8);
    const bf16x8* wp = reinterpret_cast<const bf16x8*>(Wb + (o0 + fr) * NF + quad * 8);

    f32x4 acc = {0.f, 0.f, 0.f, 0.f};
#pragma unroll
    for (int k = 0; k < 16; ++k) {
        bf16x8 a = xa[k * 4];
        bf16x8 b = wp[k * 4];
        acc = __builtin_amdgcn_mfma_f32_16x16x32_bf16(a, b, acc, 0, 0, 0);
    }
#pragma unroll
    for (int r = 0; r < 4; ++r)
        tile[wave][quad * 4 + r][fr] = (_Float16)acc[r];
    __syncthreads();
    int orow = lane >> 2;
    int li = (lane & 3) * 4;
    half4 o4 = { tile[wave][li][orow], tile[wave][li + 1][orow],
                 tile[wave][li + 2][orow], tile[wave][li + 3][orow] };
    *reinterpret_cast<half4*>(hT + (o0 + orow) * NROW + i0 + li) = o4;
}

// ---------------------------------------------------------------------------
// Stage 2: e_srcT[h][i], e_dstT[h][i] from hT (coalesced row reads) + fused
// per-head global max. Grid dim3(12, 8).
// ---------------------------------------------------------------------------
__global__ __launch_bounds__(256) void gat_edges(const _Float16* __restrict__ hT,
                                                 const float* __restrict__ a_src,
                                                 const float* __restrict__ a_dst,
                                                 float* __restrict__ e_srcT,
                                                 float* __restrict__ e_dstT,
                                                 unsigned* __restrict__ maxkey) {
    int hh = blockIdx.y;
    int i = blockIdx.x * 256 + threadIdx.x;
    float ps = 0.f, pd = 0.f;
#pragma unroll
    for (int d = 0; d < ND; ++d) {
        float hv = (float)hT[(hh * ND + d) * NROW + i];
        ps += hv * a_src[hh * ND + d];
        pd += hv * a_dst[hh * ND + d];
    }
    e_srcT[hh * NROW + i] = ps;
    e_dstT[hh * NROW + i] = pd;
    float mx = pd;
#pragma unroll
    for (int off = 1; off < 64; off <<= 1) mx = fmaxf(mx, __shfl_xor(mx, off, 64));
    if ((threadIdx.x & 63) == 0) atomicMax(&maxkey[hh], gat_enc_key(mx));
}

// ---------------------------------------------------------------------------
// Stage 3: masked softmax-PV with 32x32x16 FP16 MFMA.
// Key change vs previous version: leaky_relu(z) = max(z, 0.2z) for ALL z, and
// exp is monotone, so p = pos ? P*A : Q*C  ==  max(P*A, Q*C).  This removes
// the per-element compare/select chain and lets the whole p-compute run in
// packed f16: v_pk_mul_f16 + v_pk_max_f16 + bfe/bfi mask + v_dot2_f32_f16
// for den (f32 accumulate). af fragment is a free bitcast of the masked
// words. VALU per js drops ~110 instrs -> ~35.
// Block = 4 waves x 32 i-rows = 128 i; LDS-staged 64-j hT chunks, double-
// buffered. Grid: 24 i-blocks x 4 jc x 8 heads = 768 blocks, 256 thr.
// ---------------------------------------------------------------------------
__global__ __launch_bounds__(256) void gat_attn(const unsigned* __restrict__ bits,
                                                const float* __restrict__ e_srcT,
                                                const float* __restrict__ e_dstT,
                                                const unsigned* __restrict__ maxkey,
                                                const _Float16* __restrict__ hT,
                                                _Float16* __restrict__ num,
                                                float* __restrict__ den) {
    constexpr int JCHUNK = NROW / 4;         // 768
    constexpr int NC = JCHUNK / 64;          // 12 chunks of 64 j
    __shared__ unsigned lds_P[JCHUNK / 2];               // 1.5 KB (half2 pairs)
    __shared__ unsigned lds_Q[JCHUNK / 2];               // 1.5 KB
    __shared__ __align__(16) _Float16 hbuf[2][4096];     // 2 x 8 KB
    int b = blockIdx.x;
    int head = b & 7;
    int jc = (b >> 3) & 3;
    int i0 = ((b >> 3) >> 2) * 128;
    int jbase = jc * JCHUNK;
    int tid = threadIdx.x;
    int wave = tid >> 6;
    int lane = tid & 63;
    int half = lane >> 5;
    int l31 = lane & 31;

    float Mg = gat_dec_key(maxkey[head]);
    for (int p = tid; p < JCHUNK / 2; p += 256) {
        float t0 = e_dstT[head * NROW + jbase + 2 * p] - Mg;      // <= 0
        float t1 = e_dstT[head * NROW + jbase + 2 * p + 1] - Mg;
        half2v P = { (_Float16)__expf(t0), (_Float16)__expf(t1) };
        half2v Q = { (_Float16)__expf(0.2f * t0), (_Float16)__expf(0.2f * t1) };
        lds_P[p] = __builtin_bit_cast(unsigned, P);
        lds_Q[p] = __builtin_bit_cast(unsigned, Q);
    }

    int irow = i0 + wave * 32 + l31;
    float u = e_srcT[head * NROW + irow] + Mg;
    float Af = (u > 0.f) ? 1.f : __expf(0.8f * u);
    float Cf = (u > 0.f) ? __expf(-0.8f * u) : 1.f;
    _Float16 Ah = (_Float16)Af, Ch = (_Float16)Cf;
    half2v A2 = { Ah, Ah };
    half2v C2 = { Ch, Ch };
    const half2v one2 = { (_Float16)1.f, (_Float16)1.f };
    const unsigned* brow = bits + irow * 96 + jc * (JCHUNK / 32);

    // staging: 512 slots of 16 B; slot s: js=s>>7, dh=(s>>6)&1, sl=s&63;
    // thread t stages slots t and t+256.
    int s0 = tid, s1 = tid + 256;
    const _Float16* gp0 = hT + (head * ND + ((s0 >> 6) & 1) * 32 + (s0 & 31)) * NROW
                             + jbase + (s0 >> 7) * 16 + ((s0 >> 5) & 1) * 8;
    const _Float16* gp1 = hT + (head * ND + ((s1 >> 6) & 1) * 32 + (s1 & 31)) * NROW
                             + jbase + (s1 >> 7) * 16 + ((s1 >> 5) & 1) * 8;
    *reinterpret_cast<half8*>(&hbuf[0][tid * 8])         = *reinterpret_cast<const half8*>(gp0);
    *reinterpret_cast<half8*>(&hbuf[0][(tid + 256) * 8]) = *reinterpret_cast<const half8*>(gp1);
    __syncthreads();

    f32x16 acc0 = {};
    f32x16 acc1 = {};
    float lsum = 0.f;
    uint2 wm = *reinterpret_cast<const uint2*>(brow);

    for (int k = 0; k < NC; ++k) {
        half8 st0, st1;
        uint2 wmn = wm;
        bool more = (k + 1 < NC);
        if (more) {
            st0 = *reinterpret_cast<const half8*>(gp0 + (k + 1) * 64);
            st1 = *reinterpret_cast<const half8*>(gp1 + (k + 1) * 64);
            wmn = *reinterpret_cast<const uint2*>(brow + (k + 1) * 2);
        }
        const _Float16* hb = &hbuf[k & 1][0];
#pragma unroll
        for (int js = 0; js < 4; ++js) {
            unsigned word = (js < 2) ? wm.x : wm.y;
            unsigned w8 = (word >> ((js & 1) * 16 + half * 8)) & 0xffu;
            uint4 Pv = *reinterpret_cast<const uint4*>(&lds_P[k * 32 + js * 8 + half * 4]);
            uint4 Qv = *reinterpret_cast<const uint4*>(&lds_Q[k * 32 + js * 8 + half * 4]);
            unsigned pr[4] = { Pv.x, Pv.y, Pv.z, Pv.w };
            unsigned qr[4] = { Qv.x, Qv.y, Qv.z, Qv.w };
            unsigned am[4];
#pragma unroll
            for (int t = 0; t < 4; ++t) {
                half2v pp = __builtin_bit_cast(half2v, pr[t]) * A2;   // v_pk_mul_f16
                half2v qq = __builtin_bit_cast(half2v, qr[t]) * C2;   // v_pk_mul_f16
                half2v mx = __builtin_elementwise_max(pp, qq);        // v_pk_max_f16
                int b0 = ((int)(w8 << (31 - 2 * t))) >> 31;           // sign-spread bit 2t
                int b1 = ((int)(w8 << (30 - 2 * t))) >> 31;           // sign-spread bit 2t+1
                unsigned mk = ((unsigned)b0 & 0xFFFFu) | ((unsigned)b1 & 0xFFFF0000u);
                unsigned mr = __builtin_bit_cast(unsigned, mx) & mk;
                am[t] = mr;
                lsum = __builtin_amdgcn_fdot2(__builtin_bit_cast(half2v, mr), one2,
                                              lsum, false);           // v_dot2_f32_f16
            }
            uint4 m4 = { am[0], am[1], am[2], am[3] };
            half8 af = __builtin_bit_cast(half8, m4);                 // free repack
            half8 v0 = *reinterpret_cast<const half8*>(hb + (js * 128 + lane) * 8);
            half8 v1 = *reinterpret_cast<const half8*>(hb + (js * 128 + 64 + lane) * 8);
            acc0 = __builtin_amdgcn_mfma_f32_32x32x16_f16(af, v0, acc0, 0, 0, 0);
            acc1 = __builtin_amdgcn_mfma_f32_32x32x16_f16(af, v1, acc1, 0, 0, 0);
        }
        if (more) {
            *reinterpret_cast<half8*>(&hbuf[(k + 1) & 1][tid * 8])         = st0;
            *reinterpret_cast<half8*>(&hbuf[(k + 1) & 1][(tid + 256) * 8]) = st1;
        }
        wm = wmn;
        __syncthreads();
    }

    // den: lane owns row irow (halves hold partial sums over their k-halves)
    lsum += __shfl_xor(lsum, 32, 64);
    if (half == 0)
        den[(jc * NROW + irow) * NH + head] = lsum;

    // num (f16): C/D col = d = dh*32 + l31; row = (reg&3)+8*(reg>>2)+4*half
#pragma unroll
    for (int reg = 0; reg < 16; ++reg) {
        int rowl = (reg & 3) + 8 * (reg >> 2) + 4 * half;
        long ob = (long)(jc * NROW + i0 + wave * 32 + rowl) * NF + head * ND + l31;
        num[ob]      = (_Float16)acc0[reg];
        num[ob + 32] = (_Float16)acc1[reg];
    }
}

// ---------------------------------------------------------------------------
// Stage 4: out[i,c..c+7] = sum_jc num[jc][i][c..] / sum_jc den[jc][i][c>>6]
// Vectorized: one thread = 8 consecutive c (half8 loads, float4 stores).
// Grid 768 x 256.
// ---------------------------------------------------------------------------
__global__ __launch_bounds__(256) void gat_final(const _Float16* __restrict__ num,
                                                 const float* __restrict__ den,
                                                 float* __restrict__ out) {
    int idx = (blockIdx.x * 256 + threadIdx.x) * 8;   // 0 .. NROW*NF step 8
    int i = idx >> 9;
    int c = idx & 511;
    int head = c >> 6;
    half8 n0 = *reinterpret_cast<const half8*>(num + (long)i * NF + c);
    half8 n1 = *reinterpret_cast<const half8*>(num + (long)(NROW + i) * NF + c);
    half8 n2 = *reinterpret_cast<const half8*>(num + (long)(2 * NROW + i) * NF + c);
    half8 n3 = *reinterpret_cast<const half8*>(num + (long)(3 * NROW + i) * NF + c);
    float ds = den[i * NH + head] + den[(NROW + i) * NH + head]
             + den[(2 * NROW + i) * NH + head] + den[(3 * NROW + i) * NH + head];
    float inv = 1.0f / fmaxf(ds, 1e-30f);
    float r0 = ((float)n0[0] + (float)n1[0] + (float)n2[0] + (float)n3[0]) * inv;
    float r1 = ((float)n0[1] + (float)n1[1] + (float)n2[1] + (float)n3[1]) * inv;
    float r2 = ((float)n0[2] + (float)n1[2] + (float)n2[2] + (float)n3[2]) * inv;
    float r3 = ((float)n0[3] + (float)n1[3] + (float)n2[3] + (float)n3[3]) * inv;
    float r4 = ((float)n0[4] + (float)n1[4] + (float)n2[4] + (float)n3[4]) * inv;
    float r5 = ((float)n0[5] + (float)n1[5] + (float)n2[5] + (float)n3[5]) * inv;
    float r6 = ((float)n0[6] + (float)n1[6] + (float)n2[6] + (float)n3[6]) * inv;
    float r7 = ((float)n0[7] + (float)n1[7] + (float)n2[7] + (float)n3[7]) * inv;
    float4 o0 = { r0, r1, r2, r3 };
    float4 o1 = { r4, r5, r6, r7 };
    *reinterpret_cast<float4*>(out + idx)     = o0;
    *reinterpret_cast<float4*>(out + idx + 4) = o1;
}

// ---------------------------------------------------------------------------
extern "C" void kernel_launch(void* const* d_in, const int* in_sizes, int n_in,
                              void* d_out, int out_size, void* d_ws, size_t ws_size,
                              hipStream_t stream) {
    const float* x_raw  = (const float*)d_in[0];
    const int*   adj    = (const int*)d_in[1];
    const float* W_raw  = (const float*)d_in[2];
    const float* as_raw = (const float*)d_in[3];
    const float* ad_raw = (const float*)d_in[4];
    float* out = (float*)d_out;

    char* ws = (char*)d_ws;
    _Float16* hT     = (_Float16*)(ws);                  // 3,145,728 B
    float*    e_srcT = (float*)(ws + 3145728);           //    98,304 B
    float*    e_dstT = (float*)(ws + 3244032);           //    98,304 B
    unsigned* maxkey = (unsigned*)(ws + 3342336);        //        64 B
    unsigned* bits   = (unsigned*)(ws + 3342400);        // 1,179,648 B
    __bf16*   xb     = (__bf16*)(ws + 4522048);          // 3,145,728 B
    __bf16*   Wb     = (__bf16*)(ws + 7667776);          //   524,288 B
    _Float16* num    = (_Float16*)(ws + 8192064);        // 12,582,912 B (f16)
    float*    den    = (float*)(ws + 20774976);          //   393,216 B
    // total 21,168,192 B (<= previously-verified capacity)

    gat_prep<<<4864, 256, 0, stream>>>(x_raw, W_raw, adj, xb, Wb,
                                       (unsigned long long*)bits, maxkey);
    gat_gemm<<<1536, 256, 0, stream>>>(xb, Wb, hT);
    gat_edges<<<dim3(12, 8), 256, 0, stream>>>(hT, as_raw, ad_raw, e_srcT, e_dstT, maxkey);
    gat_attn<<<24 * 4 * 8, 256, 0, stream>>>(bits, e_srcT, e_dstT, maxkey, hT, num, den);
    gat_final<<<NROW * NF / 2048, 256, 0, stream>>>(num, den, out);
}

// Round 2
// 140.651 us; speedup vs baseline: 1.1452x; 1.0517x over previous
//
#include <hip/hip_runtime.h>
#include <hip/hip_bf16.h>

typedef __bf16 bf16x8 __attribute__((ext_vector_type(8)));
typedef __bf16 bf16x4 __attribute__((ext_vector_type(4)));
typedef _Float16 half8 __attribute__((ext_vector_type(8)));
typedef _Float16 half4 __attribute__((ext_vector_type(4)));
typedef _Float16 half2v __attribute__((ext_vector_type(2)));
typedef float f32x4 __attribute__((ext_vector_type(4)));
typedef float f32x16 __attribute__((ext_vector_type(16)));

#define NROW 3072
#define NF 512            // IN_F == H*D == 512
#define NH 8
#define ND 64
#define GEMM_BLOCKS 384

// Order-preserving float<->uint key for atomicMax over signed floats.
__device__ __forceinline__ unsigned gat_enc_key(float f) {
    unsigned u = __float_as_uint(f);
    return (f < 0.f) ? ~u : (u | 0x80000000u);
}
__device__ __forceinline__ float gat_dec_key(unsigned k) {
    unsigned u = (k & 0x80000000u) ? (k ^ 0x80000000u) : ~k;
    return __uint_as_float(u);
}

// ---------------------------------------------------------------------------
// Stage 0: convert x,W fp32->bf16 (float4) + maxkey init. 1792 blocks.
// (bitpack moved into the gemm kernel so its HBM phase overlaps gemm's
// L2-bound phase.)
// ---------------------------------------------------------------------------
__global__ __launch_bounds__(256) void gat_prep(const float* __restrict__ x,
                                                const float* __restrict__ W,
                                                __bf16* __restrict__ xb,
                                                __bf16* __restrict__ Wb,
                                                unsigned* __restrict__ maxkey) {
    if (blockIdx.x == 0 && threadIdx.x < NH) maxkey[threadIdx.x] = 0u;
    int k = blockIdx.x * 256 + threadIdx.x;
    const float4* s; __bf16* d;
    if (k < 393216) { s = (const float4*)x; d = xb; }
    else { k -= 393216;  s = (const float4*)W; d = Wb; }
    float4 v = s[k];
    bf16x4 o = { (__bf16)v.x, (__bf16)v.y, (__bf16)v.z, (__bf16)v.w };
    *reinterpret_cast<bf16x4*>(d + k * 4) = o;
}

// ---------------------------------------------------------------------------
// Stage 1 (fused): blocks 0..383: h = x @ W^T via 64x64 block tiles
// (4 waves x 32x32 mfma_32x32x16_bf16, BK=64 double-buffered LDS with
// XOR-swizzled chunk layout; swizzle applied on BOTH global-source and
// LDS-read sides). Blocks 384..3455: bitpack (adj>0 || j==i) into
// bits[3072][96] — HBM-bound, overlaps the L2-bound gemm blocks.
// L2 traffic for gemm: 48 MB (vs 196 MB in the 16x16-tile version).
// ---------------------------------------------------------------------------
__global__ __launch_bounds__(256) void gat_gemm_bp(const __bf16* __restrict__ xb,
                                                   const __bf16* __restrict__ Wb,
                                                   _Float16* __restrict__ hT,
                                                   const int* __restrict__ adj,
                                                   unsigned long long* __restrict__ bits64) {
    __shared__ __align__(16) __bf16 sA[2][4096];   // 64 rows x 64 halfs per buf
    __shared__ __align__(16) __bf16 sB[2][4096];

    if (blockIdx.x >= GEMM_BLOCKS) {
        // ---- bitpack path ----
        int i = blockIdx.x - GEMM_BLOCKS;
        int wave = threadIdx.x >> 6;
        int lane = threadIdx.x & 63;
        const int* row = adj + i * NROW;
#pragma unroll
        for (int it = 0; it < 12; ++it) {
            int base = wave * 768 + it * 64;
            int j = base + lane;
            bool pred = (row[j] > 0) || (j == i);
            unsigned long long bal = __ballot(pred);
            if (lane == 0) bits64[i * 48 + (base >> 6)] = bal;
        }
        return;
    }

    // ---- gemm path ----
    int b = blockIdx.x;                 // 48 i-panels x 8 o-groups
    int i0 = (b >> 3) * 64;
    int o0 = (b & 7) * 64;
    int tid = threadIdx.x;
    int wave = tid >> 6;
    int lane = tid & 63;
    int half = lane >> 5;
    int l31 = lane & 31;
    int wr = wave >> 1;                 // i sub-tile (0/1)
    int wc = wave & 1;                  // o sub-tile (0/1)

    // staging slots: 512 x 16B per operand; thread t owns slots t and t+256.
    // slot v: row r=v>>3, in-row 16B position p=v&7 holds global chunk
    // cc = p ^ (r&7)  (XOR swizzle; read side applies the same XOR).
    int v0 = tid, v1 = tid + 256;
    int r0 = v0 >> 3, r1 = v1 >> 3;
    int cc0 = ((v0 & 7) ^ (r0 & 7)) << 3;    // half offset within 64-half chunk
    int cc1 = ((v1 & 7) ^ (r1 & 7)) << 3;
    const __bf16* gA0 = xb + (i0 + r0) * NF + cc0;
    const __bf16* gA1 = xb + (i0 + r1) * NF + cc1;
    const __bf16* gB0 = Wb + (o0 + r0) * NF + cc0;
    const __bf16* gB1 = Wb + (o0 + r1) * NF + cc1;

    // prologue: stage chunk 0
    {
        bf16x8 a0 = *reinterpret_cast<const bf16x8*>(gA0);
        bf16x8 a1 = *reinterpret_cast<const bf16x8*>(gA1);
        bf16x8 b0 = *reinterpret_cast<const bf16x8*>(gB0);
        bf16x8 b1 = *reinterpret_cast<const bf16x8*>(gB1);
        *reinterpret_cast<bf16x8*>(&sA[0][v0 * 8]) = a0;
        *reinterpret_cast<bf16x8*>(&sA[0][v1 * 8]) = a1;
        *reinterpret_cast<bf16x8*>(&sB[0][v0 * 8]) = b0;
        *reinterpret_cast<bf16x8*>(&sB[0][v1 * 8]) = b1;
    }
    __syncthreads();

    f32x16 acc = {};
    int arow = (wr * 32 + l31) * 64;    // half index of wave's A row
    int brow = (wc * 32 + l31) * 64;
    int sw7 = l31 & 7;

    for (int c = 0; c < 8; ++c) {
        bf16x8 na0, na1, nb0, nb1;
        bool more = (c < 7);
        if (more) {
            na0 = *reinterpret_cast<const bf16x8*>(gA0 + (c + 1) * 64);
            na1 = *reinterpret_cast<const bf16x8*>(gA1 + (c + 1) * 64);
            nb0 = *reinterpret_cast<const bf16x8*>(gB0 + (c + 1) * 64);
            nb1 = *reinterpret_cast<const bf16x8*>(gB1 + (c + 1) * 64);
        }
        const __bf16* pa = &sA[c & 1][0];
        const __bf16* pb = &sB[c & 1][0];
#pragma unroll
        for (int ks = 0; ks < 4; ++ks) {
            int q = (((ks << 1) | half) ^ sw7) << 3;
            bf16x8 a = *reinterpret_cast<const bf16x8*>(pa + arow + q);
            bf16x8 bb = *reinterpret_cast<const bf16x8*>(pb + brow + q);
            acc = __builtin_amdgcn_mfma_f32_32x32x16_bf16(a, bb, acc, 0, 0, 0);
        }
        if (more) {
            *reinterpret_cast<bf16x8*>(&sA[(c + 1) & 1][v0 * 8]) = na0;
            *reinterpret_cast<bf16x8*>(&sA[(c + 1) & 1][v1 * 8]) = na1;
            *reinterpret_cast<bf16x8*>(&sB[(c + 1) & 1][v0 * 8]) = nb0;
            *reinterpret_cast<bf16x8*>(&sB[(c + 1) & 1][v1 * 8]) = nb1;
        }
        __syncthreads();
    }

    // epilogue: per-wave 32x32 transpose through LDS (reuse staging space),
    // coalesced half8 stores to hT[o][i].
    _Float16* tt = reinterpret_cast<_Float16*>(&sA[0][0]) + wave * 1056; // 32x33
#pragma unroll
    for (int reg = 0; reg < 16; ++reg) {
        int rowl = (reg & 3) + 8 * (reg >> 2) + 4 * half;   // i_local
        tt[rowl * 33 + l31] = (_Float16)acc[reg];           // [i][o]
    }
    __syncthreads();
    int orow = lane >> 1;
    int li = (lane & 1) * 16;
    half8 h0, h1;
#pragma unroll
    for (int t = 0; t < 8; ++t) h0[t] = tt[(li + t) * 33 + orow];
#pragma unroll
    for (int t = 0; t < 8; ++t) h1[t] = tt[(li + 8 + t) * 33 + orow];
    _Float16* op = hT + (long)(o0 + wc * 32 + orow) * NROW + i0 + wr * 32 + li;
    *reinterpret_cast<half8*>(op) = h0;
    *reinterpret_cast<half8*>(op + 8) = h1;
}

// ---------------------------------------------------------------------------
// Stage 2: e_srcT[h][i], e_dstT[h][i] from hT (coalesced row reads) + fused
// per-head global max. Grid dim3(12, 8).
// ---------------------------------------------------------------------------
__global__ __launch_bounds__(256) void gat_edges(const _Float16* __restrict__ hT,
                                                 const float* __restrict__ a_src,
                                                 const float* __restrict__ a_dst,
                                                 float* __restrict__ e_srcT,
                                                 float* __restrict__ e_dstT,
                                                 unsigned* __restrict__ maxkey) {
    int hh = blockIdx.y;
    int i = blockIdx.x * 256 + threadIdx.x;
    float ps = 0.f, pd = 0.f;
#pragma unroll
    for (int d = 0; d < ND; ++d) {
        float hv = (float)hT[(hh * ND + d) * NROW + i];
        ps += hv * a_src[hh * ND + d];
        pd += hv * a_dst[hh * ND + d];
    }
    e_srcT[hh * NROW + i] = ps;
    e_dstT[hh * NROW + i] = pd;
    float mx = pd;
#pragma unroll
    for (int off = 1; off < 64; off <<= 1) mx = fmaxf(mx, __shfl_xor(mx, off, 64));
    if ((threadIdx.x & 63) == 0) atomicMax(&maxkey[hh], gat_enc_key(mx));
}

// ---------------------------------------------------------------------------
// Stage 3: masked softmax-PV with 32x32x16 FP16 MFMA, packed-f16 p-compute
// (p = max(P*A, Q*C) — exact identity for leaky_relu+exp).
// This round: den computed on the MFMA pipe via acc2 = mfma(af, ones, acc2)
// (B=1 -> every column of D is the row sum), replacing the serial v_dot2
// chain + shfl on the saturated VALU pipe.
// Grid: 24 i-blocks x 4 jc x 8 heads = 768 blocks, 256 thr.
// ---------------------------------------------------------------------------
__global__ __launch_bounds__(256) void gat_attn(const unsigned* __restrict__ bits,
                                                const float* __restrict__ e_srcT,
                                                const float* __restrict__ e_dstT,
                                                const unsigned* __restrict__ maxkey,
                                                const _Float16* __restrict__ hT,
                                                _Float16* __restrict__ num,
                                                float* __restrict__ den) {
    constexpr int JCHUNK = NROW / 4;         // 768
    constexpr int NC = JCHUNK / 64;          // 12 chunks of 64 j
    __shared__ unsigned lds_P[JCHUNK / 2];               // 1.5 KB (half2 pairs)
    __shared__ unsigned lds_Q[JCHUNK / 2];               // 1.5 KB
    __shared__ __align__(16) _Float16 hbuf[2][4096];     // 2 x 8 KB
    int b = blockIdx.x;
    int head = b & 7;
    int jc = (b >> 3) & 3;
    int i0 = ((b >> 3) >> 2) * 128;
    int jbase = jc * JCHUNK;
    int tid = threadIdx.x;
    int wave = tid >> 6;
    int lane = tid & 63;
    int half = lane >> 5;
    int l31 = lane & 31;

    float Mg = gat_dec_key(maxkey[head]);
    for (int p = tid; p < JCHUNK / 2; p += 256) {
        float t0 = e_dstT[head * NROW + jbase + 2 * p] - Mg;      // <= 0
        float t1 = e_dstT[head * NROW + jbase + 2 * p + 1] - Mg;
        half2v P = { (_Float16)__expf(t0), (_Float16)__expf(t1) };
        half2v Q = { (_Float16)__expf(0.2f * t0), (_Float16)__expf(0.2f * t1) };
        lds_P[p] = __builtin_bit_cast(unsigned, P);
        lds_Q[p] = __builtin_bit_cast(unsigned, Q);
    }

    int irow = i0 + wave * 32 + l31;
    float u = e_srcT[head * NROW + irow] + Mg;
    float Af = (u > 0.f) ? 1.f : __expf(0.8f * u);
    float Cf = (u > 0.f) ? __expf(-0.8f * u) : 1.f;
    _Float16 Ah = (_Float16)Af, Ch = (_Float16)Cf;
    half2v A2 = { Ah, Ah };
    half2v C2 = { Ch, Ch };
    const half8 ones8 = { (_Float16)1.f, (_Float16)1.f, (_Float16)1.f, (_Float16)1.f,
                          (_Float16)1.f, (_Float16)1.f, (_Float16)1.f, (_Float16)1.f };
    const unsigned* brow = bits + irow * 96 + jc * (JCHUNK / 32);

    // staging: 512 slots of 16 B; slot s: js=s>>7, dh=(s>>6)&1, sl=s&63;
    // thread t stages slots t and t+256.
    int s0 = tid, s1 = tid + 256;
    const _Float16* gp0 = hT + (head * ND + ((s0 >> 6) & 1) * 32 + (s0 & 31)) * NROW
                             + jbase + (s0 >> 7) * 16 + ((s0 >> 5) & 1) * 8;
    const _Float16* gp1 = hT + (head * ND + ((s1 >> 6) & 1) * 32 + (s1 & 31)) * NROW
                             + jbase + (s1 >> 7) * 16 + ((s1 >> 5) & 1) * 8;
    *reinterpret_cast<half8*>(&hbuf[0][tid * 8])         = *reinterpret_cast<const half8*>(gp0);
    *reinterpret_cast<half8*>(&hbuf[0][(tid + 256) * 8]) = *reinterpret_cast<const half8*>(gp1);
    __syncthreads();

    f32x16 acc0 = {};
    f32x16 acc1 = {};
    f32x16 acc2 = {};
    uint2 wm = *reinterpret_cast<const uint2*>(brow);

    for (int k = 0; k < NC; ++k) {
        half8 st0, st1;
        uint2 wmn = wm;
        bool more = (k + 1 < NC);
        if (more) {
            st0 = *reinterpret_cast<const half8*>(gp0 + (k + 1) * 64);
            st1 = *reinterpret_cast<const half8*>(gp1 + (k + 1) * 64);
            wmn = *reinterpret_cast<const uint2*>(brow + (k + 1) * 2);
        }
        const _Float16* hb = &hbuf[k & 1][0];
#pragma unroll
        for (int js = 0; js < 4; ++js) {
            unsigned word = (js < 2) ? wm.x : wm.y;
            unsigned w8 = (word >> ((js & 1) * 16 + half * 8)) & 0xffu;
            uint4 Pv = *reinterpret_cast<const uint4*>(&lds_P[k * 32 + js * 8 + half * 4]);
            uint4 Qv = *reinterpret_cast<const uint4*>(&lds_Q[k * 32 + js * 8 + half * 4]);
            unsigned pr[4] = { Pv.x, Pv.y, Pv.z, Pv.w };
            unsigned qr[4] = { Qv.x, Qv.y, Qv.z, Qv.w };
            unsigned am[4];
#pragma unroll
            for (int t = 0; t < 4; ++t) {
                half2v pp = __builtin_bit_cast(half2v, pr[t]) * A2;   // v_pk_mul_f16
                half2v qq = __builtin_bit_cast(half2v, qr[t]) * C2;   // v_pk_mul_f16
                half2v mx = __builtin_elementwise_max(pp, qq);        // v_pk_max_f16
                int b0 = ((int)(w8 << (31 - 2 * t))) >> 31;           // sign-spread bit 2t
                int b1 = ((int)(w8 << (30 - 2 * t))) >> 31;           // sign-spread bit 2t+1
                unsigned mk = ((unsigned)b0 & 0xFFFFu) | ((unsigned)b1 & 0xFFFF0000u);
                am[t] = __builtin_bit_cast(unsigned, mx) & mk;
            }
            uint4 m4 = { am[0], am[1], am[2], am[3] };
            half8 af = __builtin_bit_cast(half8, m4);                 // free repack
            half8 v0 = *reinterpret_cast<const half8*>(hb + (js * 128 + lane) * 8);
            half8 v1 = *reinterpret_cast<const half8*>(hb + (js * 128 + 64 + lane) * 8);
            acc0 = __builtin_amdgcn_mfma_f32_32x32x16_f16(af, v0, acc0, 0, 0, 0);
            acc1 = __builtin_amdgcn_mfma_f32_32x32x16_f16(af, v1, acc1, 0, 0, 0);
            acc2 = __builtin_amdgcn_mfma_f32_32x32x16_f16(af, ones8, acc2, 0, 0, 0);
        }
        if (more) {
            *reinterpret_cast<half8*>(&hbuf[(k + 1) & 1][tid * 8])         = st0;
            *reinterpret_cast<half8*>(&hbuf[(k + 1) & 1][(tid + 256) * 8]) = st1;
        }
        wm = wmn;
        __syncthreads();
    }

    // den from acc2: with B=ones, D[i][d] = sum_j af[i][j] for every d, so
    // column 0 (lane l31==0 of each half) holds the row sums.
    if (l31 == 0) {
#pragma unroll
        for (int reg = 0; reg < 16; ++reg) {
            int rowl = (reg & 3) + 8 * (reg >> 2) + 4 * half;
            den[(long)(jc * NROW + i0 + wave * 32 + rowl) * NH + head] = acc2[reg];
        }
    }

    // num (f16): C/D col = d = dh*32 + l31; row = (reg&3)+8*(reg>>2)+4*half
#pragma unroll
    for (int reg = 0; reg < 16; ++reg) {
        int rowl = (reg & 3) + 8 * (reg >> 2) + 4 * half;
        long ob = (long)(jc * NROW + i0 + wave * 32 + rowl) * NF + head * ND + l31;
        num[ob]      = (_Float16)acc0[reg];
        num[ob + 32] = (_Float16)acc1[reg];
    }
}

// ---------------------------------------------------------------------------
// Stage 4: out[i,c..c+7] = sum_jc num[jc][i][c..] / sum_jc den[jc][i][c>>6]
// Vectorized: one thread = 8 consecutive c (half8 loads, float4 stores).
// Grid 768 x 256.
// ---------------------------------------------------------------------------
__global__ __launch_bounds__(256) void gat_final(const _Float16* __restrict__ num,
                                                 const float* __restrict__ den,
                                                 float* __restrict__ out) {
    int idx = (blockIdx.x * 256 + threadIdx.x) * 8;   // 0 .. NROW*NF step 8
    int i = idx >> 9;
    int c = idx & 511;
    int head = c >> 6;
    half8 n0 = *reinterpret_cast<const half8*>(num + (long)i * NF + c);
    half8 n1 = *reinterpret_cast<const half8*>(num + (long)(NROW + i) * NF + c);
    half8 n2 = *reinterpret_cast<const half8*>(num + (long)(2 * NROW + i) * NF + c);
    half8 n3 = *reinterpret_cast<const half8*>(num + (long)(3 * NROW + i) * NF + c);
    float ds = den[i * NH + head] + den[(NROW + i) * NH + head]
             + den[(2 * NROW + i) * NH + head] + den[(3 * NROW + i) * NH + head];
    float inv = 1.0f / fmaxf(ds, 1e-30f);
    float r0 = ((float)n0[0] + (float)n1[0] + (float)n2[0] + (float)n3[0]) * inv;
    float r1 = ((float)n0[1] + (float)n1[1] + (float)n2[1] + (float)n3[1]) * inv;
    float r2 = ((float)n0[2] + (float)n1[2] + (float)n2[2] + (float)n3[2]) * inv;
    float r3 = ((float)n0[3] + (float)n1[3] + (float)n2[3] + (float)n3[3]) * inv;
    float r4 = ((float)n0[4] + (float)n1[4] + (float)n2[4] + (float)n3[4]) * inv;
    float r5 = ((float)n0[5] + (float)n1[5] + (float)n2[5] + (float)n3[5]) * inv;
    float r6 = ((float)n0[6] + (float)n1[6] + (float)n2[6] + (float)n3[6]) * inv;
    float r7 = ((float)n0[7] + (float)n1[7] + (float)n2[7] + (float)n3[7]) * inv;
    float4 o0 = { r0, r1, r2, r3 };
    float4 o1 = { r4, r5, r6, r7 };
    *reinterpret_cast<float4*>(out + idx)     = o0;
    *reinterpret_cast<float4*>(out + idx + 4) = o1;
}

// ---------------------------------------------------------------------------
extern "C" void kernel_launch(void* const* d_in, const int* in_sizes, int n_in,
                              void* d_out, int out_size, void* d_ws, size_t ws_size,
                              hipStream_t stream) {
    const float* x_raw  = (const float*)d_in[0];
    const int*   adj    = (const int*)d_in[1];
    const float* W_raw  = (const float*)d_in[2];
    const float* as_raw = (const float*)d_in[3];
    const float* ad_raw = (const float*)d_in[4];
    float* out = (float*)d_out;

    char* ws = (char*)d_ws;
    _Float16* hT     = (_Float16*)(ws);                  // 3,145,728 B
    float*    e_srcT = (float*)(ws + 3145728);           //    98,304 B
    float*    e_dstT = (float*)(ws + 3244032);           //    98,304 B
    unsigned* maxkey = (unsigned*)(ws + 3342336);        //        64 B
    unsigned* bits   = (unsigned*)(ws + 3342400);        // 1,179,648 B
    __bf16*   xb     = (__bf16*)(ws + 4522048);          // 3,145,728 B
    __bf16*   Wb     = (__bf16*)(ws + 7667776);          //   524,288 B
    _Float16* num    = (_Float16*)(ws + 8192064);        // 12,582,912 B (f16)
    float*    den    = (float*)(ws + 20774976);          //   393,216 B
    // total 21,168,192 B (<= previously-verified capacity)

    gat_prep<<<1792, 256, 0, stream>>>(x_raw, W_raw, xb, Wb, maxkey);
    gat_gemm_bp<<<GEMM_BLOCKS + NROW, 256, 0, stream>>>(xb, Wb, hT, adj,
                                                        (unsigned long long*)bits);
    gat_edges<<<dim3(12, 8), 256, 0, stream>>>(hT, as_raw, ad_raw, e_srcT, e_dstT, maxkey);
    gat_attn<<<24 * 4 * 8, 256, 0, stream>>>(bits, e_srcT, e_dstT, maxkey, hT, num, den);
    gat_final<<<NROW * NF / 2048, 256, 0, stream>>>(num, den, out);
}